// Round 1
// 730.080 us; speedup vs baseline: 1.0594x; 1.0594x over previous
//
#include <hip/hip_runtime.h>
#include <math.h>

// Problem constants
#define NN 50000
#define NE 500000
#define HC 128      // HEADS*OUT_CH
#define TD 64       // TIME_DIM
#define ED 192      // EDGE_DIM
#define TILE_E 64   // edges per block in edge kernel (2 m-tiles per wave)
#define EAS 200     // ea row stride bf16: 400B (16B-aligned), 100 words = 4 mod 32 banks (2-way, free)
#define PXS 136     // proj x-tile stride bf16: 272B (16B-aligned), 68 words = 4 mod 32 banks

typedef __attribute__((ext_vector_type(8))) short bf16x8;
typedef __attribute__((ext_vector_type(4))) float f32x4;
typedef __attribute__((ext_vector_type(2))) short v2s;

__device__ __forceinline__ short f2bf(float f) {
    union { float f; unsigned u; } a; a.f = f;
    unsigned r = a.u + 0x7fff + ((a.u >> 16) & 1);   // RNE
    return (short)(r >> 16);
}
__device__ __forceinline__ float bf2f(short s) {
    union { unsigned u; float f; } a; a.u = ((unsigned)(unsigned short)s) << 16;
    return a.f;
}

// pk bf16 atomic add (2 channels per L2 atomic op)
__device__ __forceinline__ void atomic_pk_add_bf16(short* addr, float lo, float hi) {
#if __has_builtin(__builtin_amdgcn_global_atomic_fadd_v2bf16)
    v2s val; val[0] = f2bf(lo); val[1] = f2bf(hi);
    __builtin_amdgcn_global_atomic_fadd_v2bf16(
        (__attribute__((address_space(1))) v2s*)addr, val);
#else
    unsigned* p = (unsigned*)addr;
    unsigned old = *p, assumed;
    do {
        assumed = old;
        float l = bf2f((short)(assumed & 0xffff)) + lo;
        float h = bf2f((short)(assumed >> 16)) + hi;
        unsigned nv = ((unsigned)(unsigned short)f2bf(h) << 16) | (unsigned short)f2bf(l);
        old = atomicCAS(p, assumed, nv);
    } while (old != assumed);
#endif
}

// ---------------------------------------------------------------------------
// prep: x -> bf16
// ---------------------------------------------------------------------------
__global__ __launch_bounds__(256) void prep_xb(const float* __restrict__ x,
                                               short* __restrict__ xb) {
    int i = blockIdx.x * 256 + threadIdx.x;   // over NN*32 float4s
    if (i >= NN * 32) return;
    float4 v = ((const float4*)x)[i];
    short4 o; o.x = f2bf(v.x); o.y = f2bf(v.y); o.z = f2bf(v.z); o.w = f2bf(v.w);
    ((short4*)xb)[i] = o;
}

// ---------------------------------------------------------------------------
// prep: WeT[n][k] = bf16(We[k][n])  (128x192)  and
//       WT[m][n][k] = bf16(W_m[k][n]) for m in {q,k,v,skip} (4 x 128 x 128)
// ---------------------------------------------------------------------------
__global__ __launch_bounds__(256) void prep_weights(
    const float* __restrict__ We,
    const float* __restrict__ Wq, const float* __restrict__ Wk,
    const float* __restrict__ Wv, const float* __restrict__ Ws,
    short* __restrict__ WeT, short* __restrict__ WT) {
    int i = blockIdx.x * 256 + threadIdx.x;
    if (i < HC * ED) {
        int n = i / ED, kk = i % ED;
        WeT[i] = f2bf(We[(size_t)kk * HC + n]);
    }
    int j = i - HC * ED;
    if (j >= 0 && j < 4 * 128 * 128) {
        int m = j >> 14, r = j & 16383, n = r >> 7, kk = r & 127;
        const float* W = (m == 0) ? Wq : (m == 1) ? Wk : (m == 2) ? Wv : Ws;
        WT[j] = f2bf(W[kk * 128 + n]);
    }
}

// ---------------------------------------------------------------------------
// K1: MFMA projections. Block = 32 nodes, 4 waves; wave w computes output
// matrix w (q,k,v,skip) for all 32 nodes x 128 out-ch.
// q/k/v written as bf16 in MFMA-FRAGMENT layout: qb[((n*2+h)*16+c)*4 + nt]
// so the edge kernel gathers one lane's 4 channels with ONE 8B load.
// skip stays fp32 row-major (consumed once by finalize).
// ---------------------------------------------------------------------------
__global__ __launch_bounds__(256) void proj_mfma(
    const short* __restrict__ xb,     // [NN][128] bf16
    const short* __restrict__ WT,     // [4][128][128] bf16 (n-major)
    const float* __restrict__ bq, const float* __restrict__ bk,
    const float* __restrict__ bv, const float* __restrict__ bs,
    short* __restrict__ qb, short* __restrict__ kb, short* __restrict__ vb,
    float* __restrict__ skip)
{
    __shared__ short xs[32 * PXS];   // 8.7 KB
    const int t  = threadIdx.x;
    const int n0 = blockIdx.x * 32;

    for (int idx = t; idx < 32 * 16; idx += 256) {
        int m  = idx >> 4;
        int c8 = idx & 15;
        int n  = n0 + m;
        bf16x8 val = {0, 0, 0, 0, 0, 0, 0, 0};
        if (n < NN) val = ((const bf16x8*)xb)[(size_t)n * 16 + c8];
        *(bf16x8*)&xs[m * PXS + c8 * 8] = val;
    }
    __syncthreads();

    const int w    = t >> 6;
    const int lane = t & 63;
    const int c    = lane & 15;
    const int qd   = lane >> 4;
    const short* WTm = WT + (size_t)w * 16384;

    f32x4 acc[2][8];
#pragma unroll
    for (int mt = 0; mt < 2; mt++)
#pragma unroll
        for (int nt = 0; nt < 8; nt++) acc[mt][nt] = (f32x4){0.f, 0.f, 0.f, 0.f};

#pragma unroll
    for (int kb2 = 0; kb2 < 4; kb2++) {
        bf16x8 a0 = *(const bf16x8*)&xs[c * PXS + qd * 8 + kb2 * 32];
        bf16x8 a1 = *(const bf16x8*)&xs[(16 + c) * PXS + qd * 8 + kb2 * 32];
#pragma unroll
        for (int nt = 0; nt < 8; nt++) {
            bf16x8 b = *(const bf16x8*)&WTm[(size_t)(nt * 16 + c) * 128 + qd * 8 + kb2 * 32];
            acc[0][nt] = __builtin_amdgcn_mfma_f32_16x16x32_bf16(a0, b, acc[0][nt], 0, 0, 0);
            acc[1][nt] = __builtin_amdgcn_mfma_f32_16x16x32_bf16(a1, b, acc[1][nt], 0, 0, 0);
        }
    }

    const float* bias = (w == 0) ? bq : (w == 1) ? bk : (w == 2) ? bv : bs;
    float bvals[8];
#pragma unroll
    for (int nt = 0; nt < 8; nt++) bvals[nt] = bias[nt * 16 + c];

    if (w < 3) {
        short* dstb = (w == 0) ? qb : (w == 1) ? kb : vb;
#pragma unroll
        for (int mt = 0; mt < 2; mt++) {
#pragma unroll
            for (int r = 0; r < 4; r++) {
                int n = n0 + mt * 16 + qd * 4 + r;
                if (n < NN) {
#pragma unroll
                    for (int h2 = 0; h2 < 2; h2++) {
                        short4 pk4;
                        pk4.x = f2bf(acc[mt][h2 * 4 + 0][r] + bvals[h2 * 4 + 0]);
                        pk4.y = f2bf(acc[mt][h2 * 4 + 1][r] + bvals[h2 * 4 + 1]);
                        pk4.z = f2bf(acc[mt][h2 * 4 + 2][r] + bvals[h2 * 4 + 2]);
                        pk4.w = f2bf(acc[mt][h2 * 4 + 3][r] + bvals[h2 * 4 + 3]);
                        ((short4*)dstb)[(size_t)n * 32 + h2 * 16 + c] = pk4;
                    }
                }
            }
        }
    } else {
#pragma unroll
        for (int mt = 0; mt < 2; mt++) {
#pragma unroll
            for (int r = 0; r < 4; r++) {
                int n = n0 + mt * 16 + qd * 4 + r;
                if (n < NN) {
                    float* dp = skip + (size_t)n * HC + c;
#pragma unroll
                    for (int nt = 0; nt < 8; nt++)
                        dp[nt * 16] = acc[mt][nt][r] + bvals[nt];
                }
            }
        }
    }
}

// ---------------------------------------------------------------------------
// K2: MFMA edge kernel. 64-edge tile per block; wave w: head h=w>>1,
// edge-half = (w&1)*32 as two 16-edge m-tiles. q/k/v gathers are ONE 8B
// fragment-layout load per (m-tile, r, array) — 24 loads/thread issued right
// after the index barrier. Output scatter: lane-local pk-bf16 atomic pairs
// (no shuffles, no lane predication).
// ---------------------------------------------------------------------------
__global__ __launch_bounds__(256) void edge_kernel(
    const int*   __restrict__ ei,
    const float* __restrict__ tarr,
    const float* __restrict__ lastup,
    const float* __restrict__ msg,
    const float* __restrict__ time_w,
    const float* __restrict__ time_b,
    const short* __restrict__ WeT,      // [128][192] bf16
    const short* __restrict__ qb,       // fragment layout bf16
    const short* __restrict__ kb,
    const short* __restrict__ vb,
    short* __restrict__ out_bf,         // [N][2][16][4] bf16 fragment layout, pre-zeroed
    float* __restrict__ nsum)           // [N][2] fp32, pre-zeroed
{
    __shared__ short ea[TILE_E * EAS];  // 25.6 KB
    __shared__ int   srcs[TILE_E], dsts[TILE_E];
    __shared__ float relt[TILE_E];

    const int t  = threadIdx.x;
    const int e0 = blockIdx.x * TILE_E;

    if (t < TILE_E) {
        int e = e0 + t;
        int s = 0, d = -1;
        float rt = 0.f;
        if (e < NE) {
            s = ei[e];
            d = ei[NE + e];
            rt = tarr[e] - lastup[s];
        }
        srcs[t] = s; dsts[t] = d; relt[t] = rt;
    }
    __syncthreads();

    const int w    = t >> 6;
    const int h    = w >> 1;
    const int half = w & 1;
    const int lane = t & 63;
    const int qd   = lane >> 4;
    const int c    = lane & 15;
    const int hb   = h * 64;

    // --- prefetch q[dst], k[src], v[src]: one 8B fragment load each ---
    int dArr[2][4];
    short4 qg[2][4], kg[2][4], vg[2][4];
#pragma unroll
    for (int mt = 0; mt < 2; mt++) {
#pragma unroll
        for (int r = 0; r < 4; r++) {
            int le = half * 32 + mt * 16 + qd * 4 + r;
            int s  = srcs[le];
            int d  = dsts[le];
            dArr[mt][r] = d;
            int dg = (d < 0) ? 0 : d;
            qg[mt][r] = ((const short4*)qb)[(size_t)dg * 32 + h * 16 + c];
            kg[mt][r] = ((const short4*)kb)[(size_t)s  * 32 + h * 16 + c];
            vg[mt][r] = ((const short4*)vb)[(size_t)s  * 32 + h * 16 + c];
        }
    }

    // --- stage edge_attr tile (bf16) ---
    for (int idx = t; idx < TILE_E * 32; idx += 256) {
        int e  = idx >> 5;
        int c2 = idx & 31;
        float r  = relt[e];
        float c0 = __cosf(r * time_w[2 * c2]     + time_b[2 * c2]);
        float c1 = __cosf(r * time_w[2 * c2 + 1] + time_b[2 * c2 + 1]);
        short2 p; p.x = f2bf(c0); p.y = f2bf(c1);
        *(short2*)&ea[e * EAS + 2 * c2] = p;
    }
    for (int idx = t; idx < TILE_E * 32; idx += 256) {
        int e  = idx >> 5;
        int c4 = idx & 31;
        float4 m = {0.f, 0.f, 0.f, 0.f};
        if (e0 + e < NE) m = ((const float4*)msg)[(size_t)(e0 + e) * 32 + c4];
        short4 p; p.x = f2bf(m.x); p.y = f2bf(m.y); p.z = f2bf(m.z); p.w = f2bf(m.w);
        *(short4*)&ea[e * EAS + TD + 4 * c4] = p;
    }
    __syncthreads();

    // --- e = edge_attr @ We(head) via MFMA, 2 m-tiles ---
    f32x4 acc[2][4];
#pragma unroll
    for (int mt = 0; mt < 2; mt++)
#pragma unroll
        for (int nt = 0; nt < 4; nt++) acc[mt][nt] = (f32x4){0.f, 0.f, 0.f, 0.f};

    const short* bP = &WeT[(size_t)(hb + c) * ED + qd * 8];
#pragma unroll
    for (int mt = 0; mt < 2; mt++) {
        const short* aP = &ea[(half * 32 + mt * 16 + c) * EAS + qd * 8];
#pragma unroll
        for (int kb2 = 0; kb2 < 6; kb2++) {
            bf16x8 af = *(const bf16x8*)(aP + kb2 * 32);
#pragma unroll
            for (int nt = 0; nt < 4; nt++) {
                bf16x8 bw = *(const bf16x8*)(bP + (size_t)nt * 16 * ED + kb2 * 32);
                acc[mt][nt] = __builtin_amdgcn_mfma_f32_16x16x32_bf16(af, bw, acc[mt][nt], 0, 0, 0);
            }
        }
    }

    // --- attention + lane-local pk-bf16 scatter ---
#pragma unroll
    for (int mt = 0; mt < 2; mt++) {
#pragma unroll
        for (int r = 0; r < 4; r++) {
            int d = dArr[mt][r];
            float e0v = acc[mt][0][r];
            float e1v = acc[mt][1][r];
            float e2v = acc[mt][2][r];
            float e3v = acc[mt][3][r];
            float p = bf2f(qg[mt][r].x) * (bf2f(kg[mt][r].x) + e0v)
                    + bf2f(qg[mt][r].y) * (bf2f(kg[mt][r].y) + e1v)
                    + bf2f(qg[mt][r].z) * (bf2f(kg[mt][r].z) + e2v)
                    + bf2f(qg[mt][r].w) * (bf2f(kg[mt][r].w) + e3v);
            p += __shfl_xor(p, 1);
            p += __shfl_xor(p, 2);
            p += __shfl_xor(p, 4);
            p += __shfl_xor(p, 8);
            if (d >= 0) {
                float alpha = __expf(p * 0.125f);   // 1/sqrt(64)
                if (c == 0) atomicAdd(&nsum[(size_t)d * 2 + h], alpha);
                short* op = out_bf + ((size_t)d * 32 + h * 16 + c) * 4;
                float v0 = (bf2f(vg[mt][r].x) + e0v) * alpha;
                float v1 = (bf2f(vg[mt][r].y) + e1v) * alpha;
                float v2 = (bf2f(vg[mt][r].z) + e2v) * alpha;
                float v3 = (bf2f(vg[mt][r].w) + e3v) * alpha;
                atomic_pk_add_bf16(op,     v0, v1);
                atomic_pk_add_bf16(op + 2, v2, v3);
            }
        }
    }
}

// ---------------------------------------------------------------------------
// K3: out = bf16_acc(fragment layout) / (nsum + 1e-16) + skip
// ---------------------------------------------------------------------------
__global__ __launch_bounds__(256) void finalize_kernel(
    float* __restrict__ out, const short* __restrict__ out_bf,
    const float* __restrict__ nsum, const float* __restrict__ skip)
{
    int i = blockIdx.x * blockDim.x + threadIdx.x;   // over NN*32 fragment short4s
    if (i >= NN * 32) return;
    int n = i >> 5;
    int h = (i >> 4) & 1;
    int c = i & 15;
    float inv = 1.0f / (nsum[(size_t)n * 2 + h] + 1e-16f);
    short4 ob = ((const short4*)out_bf)[i];
    const float* sp = skip + (size_t)n * HC + h * 64 + c;
    float*       op = out  + (size_t)n * HC + h * 64 + c;
    op[0]  = bf2f(ob.x) * inv + sp[0];
    op[16] = bf2f(ob.y) * inv + sp[16];
    op[32] = bf2f(ob.z) * inv + sp[32];
    op[48] = bf2f(ob.w) * inv + sp[48];
}

// ---------------------------------------------------------------------------
extern "C" void kernel_launch(void* const* d_in, const int* in_sizes, int n_in,
                              void* d_out, int out_size, void* d_ws, size_t ws_size,
                              hipStream_t stream) {
    const float* x      = (const float*)d_in[0];
    const float* lastup = (const float*)d_in[1];
    const float* tarr   = (const float*)d_in[2];
    const float* msg    = (const float*)d_in[3];
    const float* time_w = (const float*)d_in[4];
    const float* time_b = (const float*)d_in[5];
    const float* Wq     = (const float*)d_in[6];
    const float* bq     = (const float*)d_in[7];
    const float* Wk     = (const float*)d_in[8];
    const float* bk     = (const float*)d_in[9];
    const float* Wv     = (const float*)d_in[10];
    const float* bv     = (const float*)d_in[11];
    const float* We     = (const float*)d_in[12];
    const float* Wskip  = (const float*)d_in[13];
    const float* bskip  = (const float*)d_in[14];
    const int*   ei     = (const int*)d_in[15];

    // ws layout: skip (fp32) | nsum (fp32) | WeT | WT | qb | kb | vb | xb(=out_bf) (bf16)
    float* ws   = (float*)d_ws;
    float* skip = ws;
    float* nsum = skip + (size_t)NN * HC;
    short* WeT  = (short*)(nsum + (size_t)NN * 2);
    short* WT   = WeT + (size_t)HC * ED;
    short* qb   = WT + (size_t)4 * 128 * 128;
    short* kb   = qb + (size_t)NN * HC;
    short* vb   = kb + (size_t)NN * HC;
    short* xb   = vb + (size_t)NN * HC;   // reused as out_bf after proj
    short* out_bf = xb;
    float* out  = (float*)d_out;

    prep_xb<<<dim3((NN * 32 + 255) / 256), 256, 0, stream>>>(x, xb);
    prep_weights<<<dim3((HC * ED + 4 * 128 * 128 + 255) / 256), 256, 0, stream>>>(
        We, Wq, Wk, Wv, Wskip, WeT, WT);

    proj_mfma<<<dim3((NN + 31) / 32), 256, 0, stream>>>(
        xb, WT, bq, bk, bv, bskip, qb, kb, vb, skip);

    // xb is dead now; reuse as bf16 fragment-layout accumulator
    hipMemsetAsync(out_bf, 0, (size_t)NN * HC * sizeof(short), stream);
    hipMemsetAsync(nsum,   0, (size_t)NN * 2  * sizeof(float), stream);

    edge_kernel<<<dim3((NE + TILE_E - 1) / TILE_E), 256, 0, stream>>>(
        ei, tarr, lastup, msg, time_w, time_b, WeT, qb, kb, vb, out_bf, nsum);

    finalize_kernel<<<dim3((NN * 32 + 255) / 256), 256, 0, stream>>>(
        out, out_bf, nsum, skip);
}